// Round 1
// baseline (154.520 us; speedup 1.0000x reference)
//
#include <hip/hip_runtime.h>
#include <hip/hip_bf16.h>
#include <cstdint>
#include <cstddef>

// Problem constants
#define BB 8192
#define UU 512
#define KPACK 1024   // D + U
#define NPACK 2048   // 4*U

using frag16 = __attribute__((ext_vector_type(8))) short;   // 8 bf16 = 16 B (4 VGPRs)
using f32x4  = __attribute__((ext_vector_type(4))) float;

__device__ inline float fast_sigmoid(float x) { return 1.0f / (1.0f + __expf(-x)); }
__device__ inline float fast_tanh(float x) {
  x = fminf(fmaxf(x, -15.f), 15.f);
  float e = __expf(-2.0f * x);
  return (1.0f - e) / (1.0f + e);
}

// packed RNE f32x2 -> bf16x2 (v_cvt_pk_bf16_f32 on gfx950 via hip_bf16.h)
__device__ inline unsigned cvt2(float lo, float hi) {
  __hip_bfloat162 b = __float22bfloat162_rn(float2{lo, hi});
  union { __hip_bfloat162 b; unsigned u; } v; v.b = b;
  return v.u;
}

// ---- merged pack kernel (UNCHANGED from verified version) ----
// blocks [0, 4096): pack A = [x | h] -> bf16 [8192][1024] row-major
// blocks [4096, 4608): pack B^T: Bt[n][k] = concat(W,R)[k][n], bf16 [2048][1024]
__global__ __launch_bounds__(256) void pack_kernel(const float* __restrict__ x,
                                                   const float* __restrict__ h,
                                                   const float* __restrict__ W,
                                                   const float* __restrict__ R,
                                                   short* __restrict__ Xp,
                                                   short* __restrict__ Bt) {
  if (blockIdx.x < 4096) {
    int idx = blockIdx.x * 256 + threadIdx.x;
    int row = idx >> 7;             // /128 chunks per row
    int k8  = (idx & 127) << 3;     // 0..1016  (wave-uniform x/h split)
    const float* src = (k8 < 512) ? (x + (size_t)row * 512 + k8)
                                  : (h + (size_t)row * 512 + (k8 - 512));
    float4 a = *(const float4*)(src);
    float4 b = *(const float4*)(src + 4);
    uint4 o;
    o.x = cvt2(a.x, a.y);
    o.y = cvt2(a.z, a.w);
    o.z = cvt2(b.x, b.y);
    o.w = cvt2(b.z, b.w);
    *(uint4*)(Xp + ((size_t)idx << 3)) = o;
  } else {
    __shared__ float tile[64][65];   // +1 pad: conflict-free transpose
    int b2 = blockIdx.x - 4096;      // 512 blocks: 32 n-tiles x 16 k-tiles
    int nb = (b2 & 31) * 64;
    int kb = (b2 >> 5) * 64;
    int t  = threadIdx.x;
#pragma unroll
    for (int rep = 0; rep < 16; ++rep) {
      int kr = rep * 4 + (t >> 6);
      int c  = t & 63;
      int kg = kb + kr;
      const float* s = (kg < 512) ? (W + (size_t)kg * 2048) : (R + (size_t)(kg - 512) * 2048);
      tile[c][kr] = s[nb + c];
    }
    __syncthreads();
#pragma unroll
    for (int rep = 0; rep < 4; ++rep) {
      int nn = rep * 16 + (t >> 4);
      int k4 = (t & 15) << 2;
      uint2 o;
      o.x = cvt2(tile[nn][k4 + 0], tile[nn][k4 + 1]);
      o.y = cvt2(tile[nn][k4 + 2], tile[nn][k4 + 3]);
      *(uint2*)(Bt + (size_t)(nb + nn) * 1024 + kb + k4) = o;
    }
  }
}

// ---- fused GEMM + LSTM pointwise, triple-buffered counted-vmcnt pipeline ----
// R-next: BM=256 x (32 units x 4 gates = 128 N cols), BK=64, 8 waves (WM=4,WN=2),
// wave-tile 64x64. Triple-buffered LDS (3 x 48 KB = 144 KB): compute buf[T%3]
// while tiles T+1,T+2 are in flight -> steady-state s_waitcnt vmcnt(6), ONE
// barrier per K-step, never drain vmcnt to 0 in the main loop (T3+T4).
// Race-free by construction: stage of tile T+2 targets buf[(T-1)%3], issued
// only after the barrier that proves all waves finished reading it.
// XOR chunk swizzle (kgx on stage / (4ks+q)^mx on read) identical to the
// verified 0-bank-conflict version. Bt layout + gate-gather formula unchanged.
__global__ __launch_bounds__(512, 2) void lstm_mfma_kernel(
    const short* __restrict__ A,     // bf16 [8192][1024]
    const short* __restrict__ Bt,    // bf16 [2048][1024], row n = z column
    const float* __restrict__ bias,  // [2048]
    const float* __restrict__ cprev, // [8192][512]
    float* __restrict__ out)         // h, h, c concatenated
{
  // 3 buffers x (A: 256x64 = 16384 shorts, B: 128x64 = 8192 shorts) = 144 KB
  __shared__ short lds[3 * 24576];

  const int tid  = threadIdx.x;
  const int lane = tid & 63;
  const int wave = tid >> 6;     // 0..7
  const int wm   = wave & 3;     // m-group: rows wm*64 .. +63
  const int wn   = wave >> 2;    // n-group: cols wn*64 .. +63
  const int bm   = blockIdx.x;   // 0..31  (256 rows)
  const int bn   = blockIdx.y;   // 0..15  (128 cols = 32 units x 4 gates)

  // staging decomposition: 8 lanes per 128B row, xor-swizzle k-chunks.
  const int r8  = lane >> 3;
  const int kg  = lane & 7;
  const int kgx = kg ^ r8;

  const short* ga[4];
  int la_off[4];
#pragma unroll
  for (int t = 0; t < 4; ++t) {
    int rowl = wave * 32 + t * 8 + r8;            // 0..255
    ga[t] = A + (size_t)(bm * 256 + rowl) * 1024 + kgx * 8;
    la_off[t] = (wave * 32 + t * 8) * 64;
  }
  const short* gb[2];
  int lb_off[2];
#pragma unroll
  for (int t = 0; t < 2; ++t) {
    int rowl = wave * 16 + t * 8 + r8;            // 0..127
    int u    = bn * 32 + ((rowl >> 6) << 4) + (rowl & 15);
    int gate = (rowl >> 4) & 3;
    gb[t] = Bt + (size_t)(gate * 512 + u) * 1024 + kgx * 8;
    lb_off[t] = (wave * 16 + t * 8) * 64;
  }

  const int q   = lane >> 4;
  const int c16 = lane & 15;
  const int mx  = c16 & 7;

  // issue 6 global_load_lds for K-tile T into LDS buffer bi (the ONLY vmem
  // ops in the loop -> vmcnt counting below stays exact).
  auto STAGE = [&](int T, int bi) {
    const int k0 = T * 64;
    short* base = &lds[bi * 24576];
#pragma unroll
    for (int t = 0; t < 4; ++t)
      __builtin_amdgcn_global_load_lds(
          (const __attribute__((address_space(1))) void*)(ga[t] + k0),
          (__attribute__((address_space(3))) void*)(base + la_off[t]), 16, 0, 0);
#pragma unroll
    for (int t = 0; t < 2; ++t)
      __builtin_amdgcn_global_load_lds(
          (const __attribute__((address_space(1))) void*)(gb[t] + k0),
          (__attribute__((address_space(3))) void*)(base + 16384 + lb_off[t]), 16, 0, 0);
  };

  f32x4 acc[4][4];
#pragma unroll
  for (int i = 0; i < 4; ++i)
#pragma unroll
    for (int j = 0; j < 4; ++j)
      acc[i][j] = f32x4{0.f, 0.f, 0.f, 0.f};

  STAGE(0, 0);
  STAGE(1, 1);

  int rb = 0;
  for (int T = 0; T < 16; ++T) {
    // outstanding here: tile T (6 loads, oldest) + tile T+1 (6). Wait for the
    // oldest 6 only -> tile T landed, T+1 stays in flight across the barrier.
    if (T < 15) asm volatile("s_waitcnt vmcnt(6)" ::: "memory");
    else        asm volatile("s_waitcnt vmcnt(0)" ::: "memory");
    __builtin_amdgcn_s_barrier();   // all waves' tile-T loads landed; all waves
                                    // done reading buf[(T-1)%3] (= (T+2)%3)
    if (T + 2 < 16) {
      int wb = rb + 2; if (wb >= 3) wb -= 3;
      STAGE(T + 2, wb);             // issue-early: lands ~2 iterations later
    }
    const short* la = &lds[rb * 24576];
    const short* lb = la + 16384;
    __builtin_amdgcn_s_setprio(1);
#pragma unroll
    for (int ks = 0; ks < 2; ++ks) {
      const int ch8 = ((((ks << 2) + q) ^ mx) << 3);   // swizzled 16B chunk
      frag16 af[4], bfv[4];
#pragma unroll
      for (int i = 0; i < 4; ++i)
        af[i] = *(const frag16*)(la + (wm * 64 + i * 16 + c16) * 64 + ch8);
#pragma unroll
      for (int j = 0; j < 4; ++j)
        bfv[j] = *(const frag16*)(lb + (wn * 64 + j * 16 + c16) * 64 + ch8);
#pragma unroll
      for (int i = 0; i < 4; ++i)
#pragma unroll
        for (int j = 0; j < 4; ++j)
          acc[i][j] = __builtin_amdgcn_mfma_f32_16x16x32_bf16(af[i], bfv[j], acc[i][j], 0, 0, 0);
    }
    __builtin_amdgcn_s_setprio(0);
    rb = (rb == 2) ? 0 : rb + 1;
  }

  // epilogue: lane-local LSTM pointwise. col=lane&15 -> unit, frag col j -> gate.
  const int u = bn * 32 + wn * 16 + c16;
  const float b0 = bias[u];
  const float b1 = bias[512 + u];
  const float b2 = bias[1024 + u];
  const float b3 = bias[1536 + u];
  float* outh0 = out;
  float* outh1 = out + (size_t)BB * UU;
  float* outc  = out + (size_t)2 * BB * UU;

#pragma unroll
  for (int i = 0; i < 4; ++i) {
    int row0 = bm * 256 + wm * 64 + i * 16 + q * 4;
#pragma unroll
    for (int r = 0; r < 4; ++r) {
      size_t off = (size_t)(row0 + r) * UU + u;
      float z0 = acc[i][0][r] + b0;
      float z1 = acc[i][1][r] + b1;
      float z2 = acc[i][2][r] + b2;
      float z3 = acc[i][3][r] + b3;
      float ig = fast_sigmoid(z0);
      float fg = fast_sigmoid(z1);
      float gg = fast_tanh(z2);
      float og = fast_sigmoid(z3);
      float cp = cprev[off];
      float cc = fg * cp + ig * gg;
      float hh = og * fast_tanh(cc);
      outh0[off] = hh;
      outh1[off] = hh;
      outc[off]  = cc;
    }
  }
}

extern "C" void kernel_launch(void* const* d_in, const int* in_sizes, int n_in,
                              void* d_out, int out_size, void* d_ws, size_t ws_size,
                              hipStream_t stream) {
  const float* x  = (const float*)d_in[0];
  const float* h  = (const float*)d_in[1];
  const float* c  = (const float*)d_in[2];
  const float* W  = (const float*)d_in[3];
  const float* R  = (const float*)d_in[4];
  const float* b  = (const float*)d_in[5];
  float* out = (float*)d_out;

  short* Xp = (short*)d_ws;                        // 16 MB bf16 [8192][1024]
  short* Bt = Xp + (size_t)BB * KPACK;             // 4 MB  bf16 [2048][1024]

  pack_kernel<<<4608, 256, 0, stream>>>(x, h, W, R, Xp, Bt);
  lstm_mfma_kernel<<<dim3(32, 16), 512, 0, stream>>>(Xp, Bt, b, c, out);
}

// Round 2
// 153.149 us; speedup vs baseline: 1.0089x; 1.0089x over previous
//
#include <hip/hip_runtime.h>
#include <hip/hip_bf16.h>
#include <cstdint>
#include <cstddef>

// Problem constants
#define BB 8192
#define UU 512
#define KPACK 1024   // D + U
#define NPACK 2048   // 4*U

using frag16 = __attribute__((ext_vector_type(8))) short;   // 8 bf16 = 16 B (4 VGPRs)
using f32x4  = __attribute__((ext_vector_type(4))) float;

__device__ inline float fast_sigmoid(float x) { return 1.0f / (1.0f + __expf(-x)); }
__device__ inline float fast_tanh(float x) {
  x = fminf(fmaxf(x, -15.f), 15.f);
  float e = __expf(-2.0f * x);
  return (1.0f - e) / (1.0f + e);
}

// packed RNE f32x2 -> bf16x2 (v_cvt_pk_bf16_f32 on gfx950 via hip_bf16.h)
__device__ inline unsigned cvt2(float lo, float hi) {
  __hip_bfloat162 b = __float22bfloat162_rn(float2{lo, hi});
  union { __hip_bfloat162 b; unsigned u; } v; v.b = b;
  return v.u;
}

// ---- merged pack kernel (UNCHANGED from verified version) ----
__global__ __launch_bounds__(256) void pack_kernel(const float* __restrict__ x,
                                                   const float* __restrict__ h,
                                                   const float* __restrict__ W,
                                                   const float* __restrict__ R,
                                                   short* __restrict__ Xp,
                                                   short* __restrict__ Bt) {
  if (blockIdx.x < 4096) {
    int idx = blockIdx.x * 256 + threadIdx.x;
    int row = idx >> 7;             // /128 chunks per row
    int k8  = (idx & 127) << 3;     // 0..1016  (wave-uniform x/h split)
    const float* src = (k8 < 512) ? (x + (size_t)row * 512 + k8)
                                  : (h + (size_t)row * 512 + (k8 - 512));
    float4 a = *(const float4*)(src);
    float4 b = *(const float4*)(src + 4);
    uint4 o;
    o.x = cvt2(a.x, a.y);
    o.y = cvt2(a.z, a.w);
    o.z = cvt2(b.x, b.y);
    o.w = cvt2(b.z, b.w);
    *(uint4*)(Xp + ((size_t)idx << 3)) = o;
  } else {
    __shared__ float tile[64][65];   // +1 pad: conflict-free transpose
    int b2 = blockIdx.x - 4096;      // 512 blocks: 32 n-tiles x 16 k-tiles
    int nb = (b2 & 31) * 64;
    int kb = (b2 >> 5) * 64;
    int t  = threadIdx.x;
#pragma unroll
    for (int rep = 0; rep < 16; ++rep) {
      int kr = rep * 4 + (t >> 6);
      int c  = t & 63;
      int kg = kb + kr;
      const float* s = (kg < 512) ? (W + (size_t)kg * 2048) : (R + (size_t)(kg - 512) * 2048);
      tile[c][kr] = s[nb + c];
    }
    __syncthreads();
#pragma unroll
    for (int rep = 0; rep < 4; ++rep) {
      int nn = rep * 16 + (t >> 4);
      int k4 = (t & 15) << 2;
      uint2 o;
      o.x = cvt2(tile[nn][k4 + 0], tile[nn][k4 + 1]);
      o.y = cvt2(tile[nn][k4 + 2], tile[nn][k4 + 3]);
      *(uint2*)(Bt + (size_t)(nb + nn) * 1024 + kb + k4) = o;
    }
  }
}

// ---- fused GEMM + LSTM pointwise: 256x256 4-phase template (m201 port) ----
// BM=256 x BN=256 (64 units x 4 gates), BK=64. 8 waves 2M x 4N, wave-tile
// 128x64, acc[8][4] (128 VGPR). LDS 128 KB: 2 bufs x (A 256x64 + B 256x64).
// Grid (32,8) = 256 blocks = exactly 1 block/CU, one round.
// Per K-tile: 4 phases, each {ds_read frags -> raw s_barrier -> setprio(1)
// 16 MFMA setprio(0) -> raw s_barrier}; all 8 global_load_lds for tile t+1
// issued in phase 0 of tile t (~4 phases = ~2500 cy before use -> fully
// covers HBM latency), single vmcnt(0) per tile boundary waits on
// already-landed loads. Raw barriers (no __syncthreads) so loads stay in
// flight across barriers. XOR chunk swizzle identical to verified
// 0-conflict version; per-element K order identical -> numerics unchanged.
__global__ __launch_bounds__(512, 2) void lstm_mfma_kernel(
    const short* __restrict__ A,     // bf16 [8192][1024]
    const short* __restrict__ Bt,    // bf16 [2048][1024], row n = z column
    const float* __restrict__ bias,  // [2048]
    const float* __restrict__ cprev, // [8192][512]
    float* __restrict__ out)         // h, h, c concatenated
{
  // per buffer: A [256][64] = 16384 shorts, then B [256][64] = 16384 shorts
  __shared__ short lds[2 * 32768];

  const int tid  = threadIdx.x;
  const int lane = tid & 63;
  const int wave = tid >> 6;     // 0..7
  const int wm   = wave >> 2;    // 0..1  row half (128 rows)
  const int wn   = wave & 3;     // 0..3  col quarter (64 cols = 16u x 4 gates)
  const int bm   = blockIdx.x;   // 0..31
  const int bn   = blockIdx.y;   // 0..7

  // staging decomposition: 8 lanes per 128B row, xor-swizzle k-chunks.
  const int r8  = lane >> 3;
  const int kg  = lane & 7;
  const int kgx = kg ^ r8;

  const short* ga[4];
  int la_off[4];
  const short* gb[4];
  int lb_off[4];
#pragma unroll
  for (int li = 0; li < 4; ++li) {
    int rowa = li * 64 + wave * 8 + r8;           // 0..255
    ga[li] = A + (size_t)(bm * 256 + rowa) * 1024 + kgx * 8;
    la_off[li] = (li * 64 + wave * 8) * 64;
    int n = li * 64 + wave * 8 + r8;              // 0..255 (B-tile row)
    int u    = bn * 64 + ((n >> 6) << 4) + (n & 15);
    int gate = (n >> 4) & 3;
    gb[li] = Bt + (size_t)(gate * 512 + u) * 1024 + kgx * 8;
    lb_off[li] = 16384 + (li * 64 + wave * 8) * 64;
  }

  const int q   = lane >> 4;
  const int c16 = lane & 15;
  const int mx  = c16 & 7;

  // 8 global_load_lds per wave per K-tile (4 A + 4 B)
  auto STAGE = [&](int T, int bi) {
    const int k0 = T * 64;
    short* base = &lds[bi * 32768];
#pragma unroll
    for (int li = 0; li < 4; ++li)
      __builtin_amdgcn_global_load_lds(
          (const __attribute__((address_space(1))) void*)(ga[li] + k0),
          (__attribute__((address_space(3))) void*)(base + la_off[li]), 16, 0, 0);
#pragma unroll
    for (int li = 0; li < 4; ++li)
      __builtin_amdgcn_global_load_lds(
          (const __attribute__((address_space(1))) void*)(gb[li] + k0),
          (__attribute__((address_space(3))) void*)(base + lb_off[li]), 16, 0, 0);
  };

  f32x4 acc[8][4];
#pragma unroll
  for (int i = 0; i < 8; ++i)
#pragma unroll
    for (int j = 0; j < 4; ++j)
      acc[i][j] = f32x4{0.f, 0.f, 0.f, 0.f};

  STAGE(0, 0);

  // swizzled 16B-chunk offset within a 128B row, for kslice ks
  auto CH = [&](int ks) { return (((ks << 2) + q) ^ mx) << 3; };

  for (int t = 0; t < 16; ++t) {
    const int rb = t & 1;
    asm volatile("s_waitcnt vmcnt(0)" ::: "memory");  // tile-t loads landed
    __builtin_amdgcn_s_barrier();                     // ..in every wave; buf rb^1 free
    const short* la = &lds[rb * 32768];
    const short* lb = la + 16384;

    frag16 af[4][2], bq[2][2];

    // ---- phase 0: read A i0-3, B j0-1; stage tile t+1; MFMA Q0 ----
#pragma unroll
    for (int i = 0; i < 4; ++i)
#pragma unroll
      for (int ks = 0; ks < 2; ++ks)
        af[i][ks] = *(const frag16*)(la + (wm * 128 + i * 16 + c16) * 64 + CH(ks));
#pragma unroll
    for (int j = 0; j < 2; ++j)
#pragma unroll
      for (int ks = 0; ks < 2; ++ks)
        bq[j][ks] = *(const frag16*)(lb + (wn * 64 + j * 16 + c16) * 64 + CH(ks));
    if (t + 1 < 16) STAGE(t + 1, rb ^ 1);
    __builtin_amdgcn_s_barrier();
    __builtin_amdgcn_s_setprio(1);
#pragma unroll
    for (int i = 0; i < 4; ++i)
#pragma unroll
      for (int j = 0; j < 2; ++j)
#pragma unroll
        for (int ks = 0; ks < 2; ++ks)
          acc[i][j] = __builtin_amdgcn_mfma_f32_16x16x32_bf16(af[i][ks], bq[j][ks], acc[i][j], 0, 0, 0);
    __builtin_amdgcn_s_setprio(0);
    __builtin_amdgcn_s_barrier();

    // ---- phase 1: read B j2-3 (reuse A i0-3); MFMA Q1 ----
#pragma unroll
    for (int j = 0; j < 2; ++j)
#pragma unroll
      for (int ks = 0; ks < 2; ++ks)
        bq[j][ks] = *(const frag16*)(lb + (wn * 64 + (2 + j) * 16 + c16) * 64 + CH(ks));
    __builtin_amdgcn_s_barrier();
    __builtin_amdgcn_s_setprio(1);
#pragma unroll
    for (int i = 0; i < 4; ++i)
#pragma unroll
      for (int j = 0; j < 2; ++j)
#pragma unroll
        for (int ks = 0; ks < 2; ++ks)
          acc[i][2 + j] = __builtin_amdgcn_mfma_f32_16x16x32_bf16(af[i][ks], bq[j][ks], acc[i][2 + j], 0, 0, 0);
    __builtin_amdgcn_s_setprio(0);
    __builtin_amdgcn_s_barrier();

    // ---- phase 2: read A i4-7 (reuse B j2-3); MFMA Q2 ----
#pragma unroll
    for (int i = 0; i < 4; ++i)
#pragma unroll
      for (int ks = 0; ks < 2; ++ks)
        af[i][ks] = *(const frag16*)(la + (wm * 128 + (4 + i) * 16 + c16) * 64 + CH(ks));
    __builtin_amdgcn_s_barrier();
    __builtin_amdgcn_s_setprio(1);
#pragma unroll
    for (int i = 0; i < 4; ++i)
#pragma unroll
      for (int j = 0; j < 2; ++j)
#pragma unroll
        for (int ks = 0; ks < 2; ++ks)
          acc[4 + i][2 + j] = __builtin_amdgcn_mfma_f32_16x16x32_bf16(af[i][ks], bq[j][ks], acc[4 + i][2 + j], 0, 0, 0);
    __builtin_amdgcn_s_setprio(0);
    __builtin_amdgcn_s_barrier();

    // ---- phase 3: read B j0-1 (reuse A i4-7); MFMA Q3 ----
#pragma unroll
    for (int j = 0; j < 2; ++j)
#pragma unroll
      for (int ks = 0; ks < 2; ++ks)
        bq[j][ks] = *(const frag16*)(lb + (wn * 64 + j * 16 + c16) * 64 + CH(ks));
    __builtin_amdgcn_s_barrier();
    __builtin_amdgcn_s_setprio(1);
#pragma unroll
    for (int i = 0; i < 4; ++i)
#pragma unroll
      for (int j = 0; j < 2; ++j)
#pragma unroll
        for (int ks = 0; ks < 2; ++ks)
          acc[4 + i][j] = __builtin_amdgcn_mfma_f32_16x16x32_bf16(af[i][ks], bq[j][ks], acc[4 + i][j], 0, 0, 0);
    __builtin_amdgcn_s_setprio(0);
    // trailing sync provided by loop-top vmcnt+barrier
  }

  // epilogue: lane-local LSTM pointwise. unit = bn*64 + wn*16 + c16, gate = j.
  const int u = bn * 64 + wn * 16 + c16;
  const float b0 = bias[u];
  const float b1 = bias[512 + u];
  const float b2 = bias[1024 + u];
  const float b3 = bias[1536 + u];
  float* outh0 = out;
  float* outh1 = out + (size_t)BB * UU;
  float* outc  = out + (size_t)2 * BB * UU;

#pragma unroll
  for (int i = 0; i < 8; ++i) {
    int row0 = bm * 256 + wm * 128 + i * 16 + q * 4;
#pragma unroll
    for (int r = 0; r < 4; ++r) {
      size_t off = (size_t)(row0 + r) * UU + u;
      float z0 = acc[i][0][r] + b0;
      float z1 = acc[i][1][r] + b1;
      float z2 = acc[i][2][r] + b2;
      float z3 = acc[i][3][r] + b3;
      float ig = fast_sigmoid(z0);
      float fg = fast_sigmoid(z1);
      float gg = fast_tanh(z2);
      float og = fast_sigmoid(z3);
      float cp = cprev[off];
      float cc = fg * cp + ig * gg;
      float hh = og * fast_tanh(cc);
      outh0[off] = hh;
      outh1[off] = hh;
      outc[off]  = cc;
    }
  }
}

extern "C" void kernel_launch(void* const* d_in, const int* in_sizes, int n_in,
                              void* d_out, int out_size, void* d_ws, size_t ws_size,
                              hipStream_t stream) {
  const float* x  = (const float*)d_in[0];
  const float* h  = (const float*)d_in[1];
  const float* c  = (const float*)d_in[2];
  const float* W  = (const float*)d_in[3];
  const float* R  = (const float*)d_in[4];
  const float* b  = (const float*)d_in[5];
  float* out = (float*)d_out;

  short* Xp = (short*)d_ws;                        // 16 MB bf16 [8192][1024]
  short* Bt = Xp + (size_t)BB * KPACK;             // 4 MB  bf16 [2048][1024]

  pack_kernel<<<4608, 256, 0, stream>>>(x, h, W, R, Xp, Bt);
  lstm_mfma_kernel<<<dim3(32, 8), 512, 0, stream>>>(Xp, Bt, b, c, out);
}